// Round 1
// baseline (349.134 us; speedup 1.0000x reference)
//
#include <hip/hip_runtime.h>

typedef _Float16 f16;
typedef _Float16 h8_t __attribute__((ext_vector_type(8)));
typedef _Float16 h4_t __attribute__((ext_vector_type(4)));
typedef float f32x4 __attribute__((ext_vector_type(4)));

#define BS 16
#define DA 512
#define SL 1024
#define NH 8
#define DH 64

// ---------------------------------------------------------------------------
// K0: transpose + cast  src f32 [b][DA][SL]  ->  dst f16 [b][SL][DA]
// grid (SL/64, DA/64, BS), block 256
// ---------------------------------------------------------------------------
__global__ __launch_bounds__(256) void transpose_cast(const float* __restrict__ src,
                                                      f16* __restrict__ dst) {
  __shared__ float tl[64 * 68];  // stride 68: 16B-aligned rows, conflict-free
  const int b = blockIdx.z;
  const int s0 = blockIdx.x * 64;
  const int c0 = blockIdx.y * 64;
  const int t = threadIdx.x;
  // load: coalesced along s
  {
    const int sl4 = (t & 15) * 4;
    const int cr = t >> 4;  // 0..15
#pragma unroll
    for (int p = 0; p < 4; ++p) {
      const int c = cr + p * 16;
      const float4 v = *(const float4*)&src[((size_t)b * DA + c0 + c) * SL + s0 + sl4];
      *(float4*)&tl[c * 68 + sl4] = v;
    }
  }
  __syncthreads();
  // store: coalesced along c (4 consecutive c per thread, 8B f16 stores)
  {
    const int cl4 = (t & 15) * 4;
    const int sr = t >> 4;
#pragma unroll
    for (int p = 0; p < 4; ++p) {
      const int s = sr + p * 16;
      h4_t hv;
#pragma unroll
      for (int u = 0; u < 4; ++u) hv[u] = (f16)tl[(cl4 + u) * 68 + s];
      *(h4_t*)&dst[((size_t)b * SL + s0 + s) * DA + c0 + cl4] = hv;
    }
  }
}

// ---------------------------------------------------------------------------
// K1: projection GEMM.  C[gm][gn] = sum_c A[gm][c]*B[gn][c]  (+bias), f16 out
// MODE 0 (k-proj): A=W rows o (M=512),  B=XT rows s (N=1024), out kp[b][s][o], bias[gm=o]
// MODE 1 (v-proj): A=XT rows s (M=1024), B=W rows o (N=512),  out vp[b][o][s], bias[gn=o]
// grid (M/128, N/128, BS), block 256 (4 waves, each 64x64)
// ---------------------------------------------------------------------------
template <int MODE>
__global__ __launch_bounds__(256) void proj_gemm(const float* __restrict__ Wg,
                                                 const f16* __restrict__ Xg,
                                                 const float* __restrict__ bias,
                                                 f16* __restrict__ outg) {
  constexpr int MT = MODE ? SL : DA;
  constexpr int NT = MODE ? DA : SL;
  __shared__ f16 Wl[128 * 40];  // [o-row][c], stride 40 (16B aligned, <=2-way)
  __shared__ f16 Xl[128 * 40];  // [s-row][c]
  const int b = blockIdx.z;
  const int m0 = blockIdx.x * 128;
  const int n0 = blockIdx.y * 128;
  const int o_base = MODE ? n0 : m0;  // W rows are the o-dim
  const int s_base = MODE ? m0 : n0;  // X rows are the s-dim
  const int t = threadIdx.x;
  const int w = t >> 6, lane = t & 63, lr = lane & 15, lq = lane >> 4;
  const int wm = (w >> 1) * 64, wn = (w & 1) * 64;

  f32x4 acc[4][4] = {};

  for (int kt = 0; kt < 16; ++kt) {
    const int c0 = kt * 32;
    __syncthreads();
    // stage W tile (128x32 f32 -> f16)
#pragma unroll
    for (int p = 0; p < 4; ++p) {
      const int idx = p * 256 + t;
      const int row = idx >> 3, cq = (idx & 7) * 4;
      const float4 v = *(const float4*)&Wg[(size_t)(o_base + row) * DA + c0 + cq];
      h4_t hv;
      hv[0] = (f16)v.x; hv[1] = (f16)v.y; hv[2] = (f16)v.z; hv[3] = (f16)v.w;
      *(h4_t*)&Wl[row * 40 + cq] = hv;
    }
    // stage X tile (128x32 f16, 16B copies)
#pragma unroll
    for (int p = 0; p < 2; ++p) {
      const int idx = p * 256 + t;
      const int row = idx >> 2, c8 = (idx & 3) * 8;
      *(uint4*)&Xl[row * 40 + c8] =
          *(const uint4*)&Xg[((size_t)b * SL + s_base + row) * DA + c0 + c8];
    }
    __syncthreads();
    const f16* Al = MODE ? Xl : Wl;
    const f16* Bl = MODE ? Wl : Xl;
    h8_t af[4], bf[4];
#pragma unroll
    for (int i = 0; i < 4; ++i) af[i] = *(const h8_t*)&Al[(wm + i * 16 + lr) * 40 + lq * 8];
#pragma unroll
    for (int j = 0; j < 4; ++j) bf[j] = *(const h8_t*)&Bl[(wn + j * 16 + lr) * 40 + lq * 8];
#pragma unroll
    for (int i = 0; i < 4; ++i)
#pragma unroll
      for (int j = 0; j < 4; ++j)
        acc[i][j] = __builtin_amdgcn_mfma_f32_16x16x32_f16(af[i], bf[j], acc[i][j], 0, 0, 0);
  }

  // epilogue: D row = gm (4 consecutive per lane -> 8B f16 stores), col = gn
#pragma unroll
  for (int i = 0; i < 4; ++i) {
    const int gmb = m0 + wm + i * 16 + lq * 4;
    float bm[4] = {0.f, 0.f, 0.f, 0.f};
    if (MODE == 0) {
      const float4 b4 = *(const float4*)&bias[gmb];
      bm[0] = b4.x; bm[1] = b4.y; bm[2] = b4.z; bm[3] = b4.w;
    }
#pragma unroll
    for (int j = 0; j < 4; ++j) {
      const int gn = n0 + wn + j * 16 + lr;
      const float bn = (MODE == 1) ? bias[gn] : 0.f;
      h4_t hv;
#pragma unroll
      for (int r = 0; r < 4; ++r) {
        const float val = acc[i][j][r] + (MODE == 0 ? bm[r] : bn);
        hv[r] = (f16)val;
      }
      *(h4_t*)&outg[((size_t)b * NT + gn) * MT + gmb] = hv;
    }
  }
}

// ---------------------------------------------------------------------------
// K2: fused flash attention.  grid (BS*NH, SL/128), block 256 (4 waves).
// Each wave owns 32 query rows; j-tiles of 64 keys; online softmax (exp2 domain,
// GBN scale*log2(e) folded into Q; GBN shift cancels under softmax).
// ---------------------------------------------------------------------------
__global__ __launch_bounds__(256) void attn_kernel(
    const float* __restrict__ qg, const f16* __restrict__ kp, const f16* __restrict__ vp,
    const float* __restrict__ gamma, const float* __restrict__ gbns,
    const int* __restrict__ maskg, float* __restrict__ outg) {
  __shared__ f16 QP[9216];  // Q [128][72] then reused as P: 4 waves x [32][72]
  __shared__ f16 Kl[4608];  // [j 64][d], stride 72
  __shared__ f16 Vl[4608];  // [dv 64][j], stride 72
  const int bh = blockIdx.x, b = bh >> 3, h = bh & 7;
  const int i0 = blockIdx.y * 128;
  const int t = threadIdx.x, w = t >> 6, lane = t & 63, lr = lane & 15, lq = lane >> 4;
  const float scale = gamma[h] / gbns[h] * 1.44269504088896f;

  // stage Q (scaled, f32 -> f16, transposed to [i][d])
  {
    const int d = t >> 5;
    const int ii = (t & 31) * 4;
#pragma unroll
    for (int p = 0; p < 8; ++p) {
      const int dd = d + p * 8;
      const float4 v = *(const float4*)&qg[((size_t)b * DA + h * DH + dd) * SL + i0 + ii];
      QP[(ii + 0) * 72 + dd] = (f16)(v.x * scale);
      QP[(ii + 1) * 72 + dd] = (f16)(v.y * scale);
      QP[(ii + 2) * 72 + dd] = (f16)(v.z * scale);
      QP[(ii + 3) * 72 + dd] = (f16)(v.w * scale);
    }
  }
  __syncthreads();
  h8_t qf[2][2];
#pragma unroll
  for (int mi = 0; mi < 2; ++mi)
#pragma unroll
    for (int ks = 0; ks < 2; ++ks)
      qf[mi][ks] = *(const h8_t*)&QP[(w * 32 + mi * 16 + lr) * 72 + ks * 32 + lq * 8];
  __syncthreads();  // QP now free for P staging

  float m_i[2][4], l_i[2][4];
#pragma unroll
  for (int mi = 0; mi < 2; ++mi)
#pragma unroll
    for (int r = 0; r < 4; ++r) { m_i[mi][r] = -3e38f; l_i[mi][r] = 0.f; }
  f32x4 acc_o[2][4] = {};
  f16* Pw = &QP[w * 2304];

  for (int jt = 0; jt < 16; ++jt) {
    const int j0 = jt * 64;
    // stage K and V tiles (16B copies)
#pragma unroll
    for (int p = 0; p < 2; ++p) {
      const int idx = p * 256 + t;
      const int row = idx >> 3, c8 = (idx & 7) * 8;
      *(uint4*)&Kl[row * 72 + c8] =
          *(const uint4*)&kp[((size_t)b * SL + j0 + row) * DA + h * DH + c8];
      *(uint4*)&Vl[row * 72 + c8] =
          *(const uint4*)&vp[((size_t)b * DA + h * DH + row) * SL + j0 + c8];
    }
    __syncthreads();

    // S = Q K^T  (rows i, cols j)
    f32x4 sa[2][4] = {};
#pragma unroll
    for (int ks = 0; ks < 2; ++ks)
#pragma unroll
      for (int nj = 0; nj < 4; ++nj) {
        const h8_t kf = *(const h8_t*)&Kl[(nj * 16 + lr) * 72 + ks * 32 + lq * 8];
#pragma unroll
        for (int mi = 0; mi < 2; ++mi)
          sa[mi][nj] = __builtin_amdgcn_mfma_f32_16x16x32_f16(qf[mi][ks], kf, sa[mi][nj], 0, 0, 0);
      }

    // key mask
    int km[4];
#pragma unroll
    for (int nj = 0; nj < 4; ++nj) km[nj] = maskg[b * SL + j0 + nj * 16 + lr];
#pragma unroll
    for (int mi = 0; mi < 2; ++mi)
#pragma unroll
      for (int nj = 0; nj < 4; ++nj)
#pragma unroll
        for (int r = 0; r < 4; ++r)
          if (km[nj]) sa[mi][nj][r] = -1e9f;

    // online softmax (exp2 domain)
    float alpha[2][4];
#pragma unroll
    for (int mi = 0; mi < 2; ++mi)
#pragma unroll
      for (int r = 0; r < 4; ++r) {
        float mx = sa[mi][0][r];
#pragma unroll
        for (int nj = 1; nj < 4; ++nj) mx = fmaxf(mx, sa[mi][nj][r]);
        mx = fmaxf(mx, __shfl_xor(mx, 1));
        mx = fmaxf(mx, __shfl_xor(mx, 2));
        mx = fmaxf(mx, __shfl_xor(mx, 4));
        mx = fmaxf(mx, __shfl_xor(mx, 8));
        const float mn = fmaxf(m_i[mi][r], mx);
        alpha[mi][r] = exp2f(m_i[mi][r] - mn);
        m_i[mi][r] = mn;
      }
#pragma unroll
    for (int mi = 0; mi < 2; ++mi)
#pragma unroll
      for (int r = 0; r < 4; ++r) {
        float rs = 0.f;
#pragma unroll
        for (int nj = 0; nj < 4; ++nj) {
          const float pv = exp2f(sa[mi][nj][r] - m_i[mi][r]);
          sa[mi][nj][r] = pv;
          rs += pv;
        }
        rs += __shfl_xor(rs, 1);
        rs += __shfl_xor(rs, 2);
        rs += __shfl_xor(rs, 4);
        rs += __shfl_xor(rs, 8);
        l_i[mi][r] = l_i[mi][r] * alpha[mi][r] + rs;
      }
    // rescale O accumulator
#pragma unroll
    for (int mi = 0; mi < 2; ++mi)
#pragma unroll
      for (int nd = 0; nd < 4; ++nd)
#pragma unroll
        for (int r = 0; r < 4; ++r)
          acc_o[mi][nd][r] *= alpha[mi][r];
    // P -> LDS (D-layout -> [i][j] so O-GEMM can read A-fragments)
#pragma unroll
    for (int mi = 0; mi < 2; ++mi)
#pragma unroll
      for (int nj = 0; nj < 4; ++nj)
#pragma unroll
        for (int r = 0; r < 4; ++r)
          Pw[(mi * 16 + lq * 4 + r) * 72 + nj * 16 + lr] = (f16)sa[mi][nj][r];
    __syncthreads();

    // O += P V^T
#pragma unroll
    for (int jk = 0; jk < 2; ++jk) {
      h8_t pf[2];
#pragma unroll
      for (int mi = 0; mi < 2; ++mi)
        pf[mi] = *(const h8_t*)&Pw[(mi * 16 + lr) * 72 + jk * 32 + lq * 8];
#pragma unroll
      for (int nd = 0; nd < 4; ++nd) {
        const h8_t vf = *(const h8_t*)&Vl[(nd * 16 + lr) * 72 + jk * 32 + lq * 8];
#pragma unroll
        for (int mi = 0; mi < 2; ++mi)
          acc_o[mi][nd] = __builtin_amdgcn_mfma_f32_16x16x32_f16(pf[mi], vf, acc_o[mi][nd], 0, 0, 0);
      }
    }
    __syncthreads();
  }

  // epilogue: normalize, zero masked query rows, coalesced float4 stores
  float fac[2][4];
#pragma unroll
  for (int mi = 0; mi < 2; ++mi)
#pragma unroll
    for (int r = 0; r < 4; ++r) {
      const int ig = i0 + w * 32 + mi * 16 + lq * 4 + r;
      const int qm = maskg[b * SL + ig];
      fac[mi][r] = qm ? 0.f : 1.f / l_i[mi][r];
    }
#pragma unroll
  for (int mi = 0; mi < 2; ++mi)
#pragma unroll
    for (int nd = 0; nd < 4; ++nd) {
      float4 o;
      o.x = acc_o[mi][nd][0] * fac[mi][0];
      o.y = acc_o[mi][nd][1] * fac[mi][1];
      o.z = acc_o[mi][nd][2] * fac[mi][2];
      o.w = acc_o[mi][nd][3] * fac[mi][3];
      const int dv = nd * 16 + lr;
      const int ib = i0 + w * 32 + mi * 16 + lq * 4;
      *(float4*)&outg[((size_t)b * DA + h * DH + dv) * SL + ib] = o;
    }
}

// ---------------------------------------------------------------------------
extern "C" void kernel_launch(void* const* d_in, const int* in_sizes, int n_in,
                              void* d_out, int out_size, void* d_ws, size_t ws_size,
                              hipStream_t stream) {
  const float* q     = (const float*)d_in[0];
  const float* k_in  = (const float*)d_in[1];
  const float* v_in  = (const float*)d_in[2];
  const float* k_w   = (const float*)d_in[3];
  const float* k_b   = (const float*)d_in[4];
  const float* v_w   = (const float*)d_in[5];
  const float* v_b   = (const float*)d_in[6];
  const float* gamma = (const float*)d_in[7];
  // d_in[8] = gbn_bias, d_in[9] = gbn_m: shift terms cancel under softmax
  const float* gbns  = (const float*)d_in[10];
  const int*   mask  = (const int*)d_in[11];
  float* out = (float*)d_out;

  const size_t NEL = (size_t)BS * SL * DA;  // 8388608 elems
  f16* XT  = (f16*)d_ws;        // transposed input (reused for k then v)
  f16* kpw = XT + NEL;          // k projection, [b][s][o]
  f16* vpw = kpw + NEL;         // v projection, [b][o][s]
  // ws needed: 3 * 16 MiB = 48 MiB

  transpose_cast<<<dim3(SL / 64, DA / 64, BS), 256, 0, stream>>>(k_in, XT);
  proj_gemm<0><<<dim3(4, 8, BS), 256, 0, stream>>>(k_w, XT, k_b, kpw);
  transpose_cast<<<dim3(SL / 64, DA / 64, BS), 256, 0, stream>>>(v_in, XT);
  proj_gemm<1><<<dim3(8, 4, BS), 256, 0, stream>>>(v_w, XT, v_b, vpw);
  attn_kernel<<<dim3(BS * NH, SL / 128), 256, 0, stream>>>(q, kpw, vpw, gamma, gbns, mask, out);
}

// Round 2
// 325.291 us; speedup vs baseline: 1.0733x; 1.0733x over previous
//
#include <hip/hip_runtime.h>

typedef _Float16 f16;
typedef _Float16 h8_t __attribute__((ext_vector_type(8)));
typedef _Float16 h4_t __attribute__((ext_vector_type(4)));
typedef float f32x4 __attribute__((ext_vector_type(4)));
typedef float f32x16 __attribute__((ext_vector_type(16)));

#define BS 16
#define DA 512
#define SL 1024
#define NH 8
#define DH 64

// ---------------------------------------------------------------------------
// K0: transpose + cast  src f32 [b][DA][SL] -> dst f16 [b][SL][DA]
// Dual-source: gridDim.z = 2*BS handles both k and v in one launch;
// gridDim.z = BS handles only (srcA,dstA).
// LDS stride 65: conflict-free (<=2-way) in both phases.
// ---------------------------------------------------------------------------
__global__ __launch_bounds__(256) void transpose_cast(const float* __restrict__ srcA,
                                                      f16* __restrict__ dstA,
                                                      const float* __restrict__ srcB,
                                                      f16* __restrict__ dstB) {
  __shared__ float tl[64 * 65];
  const int z = blockIdx.z;
  const float* src = (z < BS) ? srcA : srcB;
  f16* dst = (z < BS) ? dstA : dstB;
  const int b = z & (BS - 1);
  const int s0 = blockIdx.x * 64;
  const int c0 = blockIdx.y * 64;
  const int t = threadIdx.x;
  // load: coalesced along s, scalar LDS stores (stride 65 rows)
  {
    const int sl4 = (t & 15) * 4;
    const int cr = t >> 4;
#pragma unroll
    for (int p = 0; p < 4; ++p) {
      const int c = cr + p * 16;
      const float4 v = *(const float4*)&src[((size_t)b * DA + c0 + c) * SL + s0 + sl4];
      tl[c * 65 + sl4 + 0] = v.x;
      tl[c * 65 + sl4 + 1] = v.y;
      tl[c * 65 + sl4 + 2] = v.z;
      tl[c * 65 + sl4 + 3] = v.w;
    }
  }
  __syncthreads();
  // store: 8 consecutive c per thread -> 16B f16 stores
  {
    const int cl8 = (t & 7) * 8;
    const int sr = t >> 3;  // 0..31
#pragma unroll
    for (int p = 0; p < 2; ++p) {
      const int s = sr + p * 32;
      h8_t hv;
#pragma unroll
      for (int u = 0; u < 8; ++u) hv[u] = (f16)tl[(cl8 + u) * 65 + s];
      *(h8_t*)&dst[((size_t)b * SL + s0 + s) * DA + c0 + cl8] = hv;
    }
  }
}

// ---------------------------------------------------------------------------
// K1: projection GEMM (unchanged from R1 — small fraction of runtime).
// MODE 0 (k-proj): out kp[b][s][o];  MODE 1 (v-proj): out vp[b][o][s]
// ---------------------------------------------------------------------------
template <int MODE>
__global__ __launch_bounds__(256) void proj_gemm(const float* __restrict__ Wg,
                                                 const f16* __restrict__ Xg,
                                                 const float* __restrict__ bias,
                                                 f16* __restrict__ outg) {
  constexpr int MT = MODE ? SL : DA;
  constexpr int NT = MODE ? DA : SL;
  __shared__ f16 Wl[128 * 40];
  __shared__ f16 Xl[128 * 40];
  const int b = blockIdx.z;
  const int m0 = blockIdx.x * 128;
  const int n0 = blockIdx.y * 128;
  const int o_base = MODE ? n0 : m0;
  const int s_base = MODE ? m0 : n0;
  const int t = threadIdx.x;
  const int w = t >> 6, lane = t & 63, lr = lane & 15, lq = lane >> 4;
  const int wm = (w >> 1) * 64, wn = (w & 1) * 64;

  f32x4 acc[4][4] = {};

  for (int kt = 0; kt < 16; ++kt) {
    const int c0 = kt * 32;
    __syncthreads();
#pragma unroll
    for (int p = 0; p < 4; ++p) {
      const int idx = p * 256 + t;
      const int row = idx >> 3, cq = (idx & 7) * 4;
      const float4 v = *(const float4*)&Wg[(size_t)(o_base + row) * DA + c0 + cq];
      h4_t hv;
      hv[0] = (f16)v.x; hv[1] = (f16)v.y; hv[2] = (f16)v.z; hv[3] = (f16)v.w;
      *(h4_t*)&Wl[row * 40 + cq] = hv;
    }
#pragma unroll
    for (int p = 0; p < 2; ++p) {
      const int idx = p * 256 + t;
      const int row = idx >> 2, c8 = (idx & 3) * 8;
      *(uint4*)&Xl[row * 40 + c8] =
          *(const uint4*)&Xg[((size_t)b * SL + s_base + row) * DA + c0 + c8];
    }
    __syncthreads();
    const f16* Al = MODE ? Xl : Wl;
    const f16* Bl = MODE ? Wl : Xl;
    h8_t af[4], bf[4];
#pragma unroll
    for (int i = 0; i < 4; ++i) af[i] = *(const h8_t*)&Al[(wm + i * 16 + lr) * 40 + lq * 8];
#pragma unroll
    for (int j = 0; j < 4; ++j) bf[j] = *(const h8_t*)&Bl[(wn + j * 16 + lr) * 40 + lq * 8];
#pragma unroll
    for (int i = 0; i < 4; ++i)
#pragma unroll
      for (int j = 0; j < 4; ++j)
        acc[i][j] = __builtin_amdgcn_mfma_f32_16x16x32_f16(af[i], bf[j], acc[i][j], 0, 0, 0);
  }

#pragma unroll
  for (int i = 0; i < 4; ++i) {
    const int gmb = m0 + wm + i * 16 + lq * 4;
    float bm[4] = {0.f, 0.f, 0.f, 0.f};
    if (MODE == 0) {
      const float4 b4 = *(const float4*)&bias[gmb];
      bm[0] = b4.x; bm[1] = b4.y; bm[2] = b4.z; bm[3] = b4.w;
    }
#pragma unroll
    for (int j = 0; j < 4; ++j) {
      const int gn = n0 + wn + j * 16 + lr;
      const float bn = (MODE == 1) ? bias[gn] : 0.f;
      h4_t hv;
#pragma unroll
      for (int r = 0; r < 4; ++r) {
        const float val = acc[i][j][r] + (MODE == 0 ? bm[r] : bn);
        hv[r] = (f16)val;
      }
      *(h4_t*)&outg[((size_t)b * NT + gn) * MT + gmb] = hv;
    }
  }
}

// ---------------------------------------------------------------------------
// K2: fused flash attention, 32x32x16 MFMA, S^T = K*Q^T formulation.
// grid (BS*NH, SL/128), block 256 (4 waves x 32 query rows).
// Per lane: one query column (i = lane&31), 32 j-values in regs ->
// in-register softmax reductions + ONE shfl_xor(32); packed b64 P stores.
// K/V staging register-prefetch pipeline, 2 barriers/tile.
// ---------------------------------------------------------------------------
__global__ __launch_bounds__(256, 3) void attn_kernel(
    const float* __restrict__ qg, const f16* __restrict__ kp, const f16* __restrict__ vp,
    const float* __restrict__ gamma, const float* __restrict__ gbns,
    const int* __restrict__ maskg, float* __restrict__ outg) {
  __shared__ f16 QP[128 * 72];   // Q staging [i][d]; wave w's rows reused as its P [i][j]
  __shared__ f16 Kl[64 * 72];    // [j][d]
  __shared__ f16 Vl[64 * 72];    // [d][j]
  __shared__ float AL[4 * 32];   // per-wave alpha/l redistribution

  const int bh = blockIdx.x, b = bh >> 3, h = bh & 7;
  const int i0 = blockIdx.y * 128;
  const int t = threadIdx.x, w = t >> 6, lane = t & 63;
  const int l5 = lane & 31, half = lane >> 5;
  const float scale = gamma[h] / gbns[h] * 1.44269504088896f;  // fold GBN scale + log2(e)

  // ---- stage Q: f32 [d][i] -> f16 [i][d], scaled
  {
    const int d = t >> 5;
    const int ii = (t & 31) * 4;
#pragma unroll
    for (int p = 0; p < 8; ++p) {
      const int dd = d + p * 8;
      const float4 v = *(const float4*)&qg[((size_t)b * DA + h * DH + dd) * SL + i0 + ii];
      QP[(ii + 0) * 72 + dd] = (f16)(v.x * scale);
      QP[(ii + 1) * 72 + dd] = (f16)(v.y * scale);
      QP[(ii + 2) * 72 + dd] = (f16)(v.z * scale);
      QP[(ii + 3) * 72 + dd] = (f16)(v.w * scale);
    }
  }
  __syncthreads();
  h8_t qf[4];  // B-operand fragments: n = i (lane&31), k = half*8 + jj
#pragma unroll
  for (int ks = 0; ks < 4; ++ks)
    qf[ks] = *(const h8_t*)&QP[(w * 32 + l5) * 72 + ks * 16 + half * 8];
  // no barrier: wave w's P region == exactly the Q rows it just read (wave-private)

  float m_i = -3e38f, l_i = 0.f;
  f32x16 acc[2] = {};  // O accumulator, nd in {0,1}: cols d = nd*32+l5
  f16* Pw = &QP[w * 32 * 72];

  // prefetch tile 0 into registers
  uint4 rk[2], rv[2];
  {
    const int row0 = t >> 3, c80 = (t & 7) * 8;
    const int row1 = (256 + t) >> 3, c81 = ((256 + t) & 7) * 8;
    rk[0] = *(const uint4*)&kp[((size_t)b * SL + row0) * DA + h * DH + c80];
    rv[0] = *(const uint4*)&vp[((size_t)b * DA + h * DH + row0) * SL + c80];
    rk[1] = *(const uint4*)&kp[((size_t)b * SL + row1) * DA + h * DH + c81];
    rv[1] = *(const uint4*)&vp[((size_t)b * DA + h * DH + row1) * SL + c81];
  }

  for (int jt = 0; jt < 16; ++jt) {
    const int j0 = jt * 64;
    __syncthreads();  // all waves done with prev tile's Kl/Vl reads
#pragma unroll
    for (int p = 0; p < 2; ++p) {
      const int idx = p * 256 + t;
      const int row = idx >> 3, c8 = (idx & 7) * 8;
      *(uint4*)&Kl[row * 72 + c8] = rk[p];
      *(uint4*)&Vl[row * 72 + c8] = rv[p];
    }
    __syncthreads();  // staged
    if (jt < 15) {    // prefetch next tile (overlaps all compute below)
      const int jn = j0 + 64;
#pragma unroll
      for (int p = 0; p < 2; ++p) {
        const int idx = p * 256 + t;
        const int row = idx >> 3, c8 = (idx & 7) * 8;
        rk[p] = *(const uint4*)&kp[((size_t)b * SL + jn + row) * DA + h * DH + c8];
        rv[p] = *(const uint4*)&vp[((size_t)b * DA + h * DH + row) * SL + jn + c8];
      }
    }

    // key-mask prefetch: j = j0 + mj*32 + q*8 + half*4 + r
    int4 mq[8];
#pragma unroll
    for (int mj = 0; mj < 2; ++mj)
#pragma unroll
      for (int q = 0; q < 4; ++q)
        mq[mj * 4 + q] = *(const int4*)&maskg[b * SL + j0 + mj * 32 + q * 8 + half * 4];

    // S^T = K * Q^T : D rows = j, cols = i
    f32x16 sa[2] = {};
#pragma unroll
    for (int ks = 0; ks < 4; ++ks) {
#pragma unroll
      for (int mj = 0; mj < 2; ++mj) {
        const h8_t kf = *(const h8_t*)&Kl[(mj * 32 + l5) * 72 + ks * 16 + half * 8];
        sa[mj] = __builtin_amdgcn_mfma_f32_32x32x16_f16(kf, qf[ks], sa[mj], 0, 0, 0);
      }
    }

    // apply key mask: reg e -> j_local = (e&3) + 8*(e>>2) + 4*half
#pragma unroll
    for (int mj = 0; mj < 2; ++mj)
#pragma unroll
      for (int q = 0; q < 4; ++q) {
        const int4 m4 = mq[mj * 4 + q];
        if (m4.x) sa[mj][q * 4 + 0] = -1e9f;
        if (m4.y) sa[mj][q * 4 + 1] = -1e9f;
        if (m4.z) sa[mj][q * 4 + 2] = -1e9f;
        if (m4.w) sa[mj][q * 4 + 3] = -1e9f;
      }

    // online softmax for column i = l5 (32 values in-reg + cross-half shuffle)
    float mx = sa[0][0];
#pragma unroll
    for (int e = 1; e < 16; ++e) mx = fmaxf(mx, sa[0][e]);
#pragma unroll
    for (int e = 0; e < 16; ++e) mx = fmaxf(mx, sa[1][e]);
    mx = fmaxf(mx, __shfl_xor(mx, 32));
    const float mn = fmaxf(m_i, mx);
    const float al = __builtin_amdgcn_exp2f(m_i - mn);
    m_i = mn;
    float rs = 0.f;
#pragma unroll
    for (int mj = 0; mj < 2; ++mj)
#pragma unroll
      for (int e = 0; e < 16; ++e) {
        const float pv = __builtin_amdgcn_exp2f(sa[mj][e] - mn);
        sa[mj][e] = pv;
        rs += pv;
      }
    rs += __shfl_xor(rs, 32);
    l_i = l_i * al + rs;

    // P -> LDS [i][j], packed b64 (4 consecutive j per reg-quad)
#pragma unroll
    for (int mj = 0; mj < 2; ++mj)
#pragma unroll
      for (int q = 0; q < 4; ++q) {
        h4_t pk;
        pk[0] = (f16)sa[mj][q * 4 + 0];
        pk[1] = (f16)sa[mj][q * 4 + 1];
        pk[2] = (f16)sa[mj][q * 4 + 2];
        pk[3] = (f16)sa[mj][q * 4 + 3];
        *(h4_t*)&Pw[l5 * 72 + mj * 32 + q * 8 + half * 4] = pk;
      }

    // redistribute alpha (per-i) to O layout via wave-private LDS
    AL[w * 32 + l5] = al;  // both halves write identical value
    f32x4 af[4];
#pragma unroll
    for (int q = 0; q < 4; ++q) af[q] = *(const f32x4*)&AL[w * 32 + q * 8 + half * 4];
#pragma unroll
    for (int nd = 0; nd < 2; ++nd)
#pragma unroll
      for (int e = 0; e < 16; ++e) acc[nd][e] *= af[e >> 2][e & 3];

    // O += P * V^T : A = P[i][j], B = V[d][j]
#pragma unroll
    for (int jk = 0; jk < 4; ++jk) {
      const h8_t pf = *(const h8_t*)&Pw[l5 * 72 + jk * 16 + half * 8];
#pragma unroll
      for (int nd = 0; nd < 2; ++nd) {
        const h8_t vf = *(const h8_t*)&Vl[(nd * 32 + l5) * 72 + jk * 16 + half * 8];
        acc[nd] = __builtin_amdgcn_mfma_f32_32x32x16_f16(pf, vf, acc[nd], 0, 0, 0);
      }
    }
  }

  // ---- epilogue: normalize, zero masked query rows, coalesced float4 stores
  AL[w * 32 + l5] = l_i;
  float fac[16];
#pragma unroll
  for (int q = 0; q < 4; ++q) {
    const f32x4 lf = *(const f32x4*)&AL[w * 32 + q * 8 + half * 4];
    const int4 mo = *(const int4*)&maskg[b * SL + i0 + w * 32 + q * 8 + half * 4];
    fac[q * 4 + 0] = mo.x ? 0.f : 1.f / lf[0];
    fac[q * 4 + 1] = mo.y ? 0.f : 1.f / lf[1];
    fac[q * 4 + 2] = mo.z ? 0.f : 1.f / lf[2];
    fac[q * 4 + 3] = mo.w ? 0.f : 1.f / lf[3];
  }
#pragma unroll
  for (int nd = 0; nd < 2; ++nd)
#pragma unroll
    for (int q = 0; q < 4; ++q) {
      float4 o;
      o.x = acc[nd][q * 4 + 0] * fac[q * 4 + 0];
      o.y = acc[nd][q * 4 + 1] * fac[q * 4 + 1];
      o.z = acc[nd][q * 4 + 2] * fac[q * 4 + 2];
      o.w = acc[nd][q * 4 + 3] * fac[q * 4 + 3];
      const int d = nd * 32 + l5;
      const int ib = i0 + w * 32 + q * 8 + half * 4;
      *(float4*)&outg[((size_t)b * DA + h * DH + d) * SL + ib] = o;
    }
}

// ---------------------------------------------------------------------------
extern "C" void kernel_launch(void* const* d_in, const int* in_sizes, int n_in,
                              void* d_out, int out_size, void* d_ws, size_t ws_size,
                              hipStream_t stream) {
  const float* q     = (const float*)d_in[0];
  const float* k_in  = (const float*)d_in[1];
  const float* v_in  = (const float*)d_in[2];
  const float* k_w   = (const float*)d_in[3];
  const float* k_b   = (const float*)d_in[4];
  const float* v_w   = (const float*)d_in[5];
  const float* v_b   = (const float*)d_in[6];
  const float* gamma = (const float*)d_in[7];
  const float* gbns  = (const float*)d_in[10];  // gbn_bias/gbn_m cancel under softmax
  const int*   mask  = (const int*)d_in[11];
  float* out = (float*)d_out;

  const size_t NEL = (size_t)BS * SL * DA;  // 8.4M elems, 16 MiB per f16 buffer

  if (ws_size >= 4 * NEL * sizeof(f16)) {
    // 64 MiB path: both transposes in one launch, then both projections
    f16* XTk = (f16*)d_ws;
    f16* XTv = XTk + NEL;
    f16* kpw = XTv + NEL;
    f16* vpw = kpw + NEL;
    transpose_cast<<<dim3(SL / 64, DA / 64, 2 * BS), 256, 0, stream>>>(k_in, XTk, v_in, XTv);
    proj_gemm<0><<<dim3(4, 8, BS), 256, 0, stream>>>(k_w, XTk, k_b, kpw);
    proj_gemm<1><<<dim3(8, 4, BS), 256, 0, stream>>>(v_w, XTv, v_b, vpw);
    attn_kernel<<<dim3(BS * NH, SL / 128), 256, 0, stream>>>(q, kpw, vpw, gamma, gbns, mask, out);
  } else {
    // 48 MiB fallback: serialize transposes through one XT buffer
    f16* XT  = (f16*)d_ws;
    f16* kpw = XT + NEL;
    f16* vpw = kpw + NEL;
    transpose_cast<<<dim3(SL / 64, DA / 64, BS), 256, 0, stream>>>(k_in, XT, k_in, XT);
    proj_gemm<0><<<dim3(4, 8, BS), 256, 0, stream>>>(k_w, XT, k_b, kpw);
    transpose_cast<<<dim3(SL / 64, DA / 64, BS), 256, 0, stream>>>(v_in, XT, v_in, XT);
    proj_gemm<1><<<dim3(8, 4, BS), 256, 0, stream>>>(v_w, XT, v_b, vpw);
    attn_kernel<<<dim3(BS * NH, SL / 128), 256, 0, stream>>>(q, kpw, vpw, gamma, gbns, mask, out);
  }
}

// Round 3
// 294.438 us; speedup vs baseline: 1.1858x; 1.1048x over previous
//
#include <hip/hip_runtime.h>

typedef _Float16 f16;
typedef _Float16 h8_t __attribute__((ext_vector_type(8)));
typedef _Float16 h4_t __attribute__((ext_vector_type(4)));
typedef float f32x4 __attribute__((ext_vector_type(4)));
typedef float f32x16 __attribute__((ext_vector_type(16)));

#define BS 16
#define DA 512
#define SL 1024
#define NH 8
#define DH 64

// ---------------------------------------------------------------------------
// K0: transpose + cast  src f32 [b][DA][SL] -> dst f16 [b][SL][DA]
// Dual-source: z in [0,BS) -> A, [BS,2BS) -> B.
// ---------------------------------------------------------------------------
__global__ __launch_bounds__(256) void transpose_cast(const float* __restrict__ srcA,
                                                      f16* __restrict__ dstA,
                                                      const float* __restrict__ srcB,
                                                      f16* __restrict__ dstB) {
  __shared__ float tl[64 * 65];
  const int z = blockIdx.z;
  const float* src = (z < BS) ? srcA : srcB;
  f16* dst = (z < BS) ? dstA : dstB;
  const int b = z & (BS - 1);
  const int s0 = blockIdx.x * 64;
  const int c0 = blockIdx.y * 64;
  const int t = threadIdx.x;
  {
    const int sl4 = (t & 15) * 4;
    const int cr = t >> 4;
#pragma unroll
    for (int p = 0; p < 4; ++p) {
      const int c = cr + p * 16;
      const float4 v = *(const float4*)&src[((size_t)b * DA + c0 + c) * SL + s0 + sl4];
      tl[c * 65 + sl4 + 0] = v.x;
      tl[c * 65 + sl4 + 1] = v.y;
      tl[c * 65 + sl4 + 2] = v.z;
      tl[c * 65 + sl4 + 3] = v.w;
    }
  }
  __syncthreads();
  {
    const int cl8 = (t & 7) * 8;
    const int sr = t >> 3;
#pragma unroll
    for (int p = 0; p < 2; ++p) {
      const int s = sr + p * 32;
      h8_t hv;
#pragma unroll
      for (int u = 0; u < 8; ++u) hv[u] = (f16)tl[(cl8 + u) * 65 + s];
      *(h8_t*)&dst[((size_t)b * SL + s0 + s) * DA + c0 + cl8] = hv;
    }
  }
}

// ---------------------------------------------------------------------------
// K1: projection GEMM with register-prefetch pipeline (global latency hidden).
// MODE 0 (k-proj): out kp[b][s][o];  MODE 1 (v-proj): out vp[b][o][s]
// ---------------------------------------------------------------------------
template <int MODE>
__global__ __launch_bounds__(256) void proj_gemm(const float* __restrict__ Wg,
                                                 const f16* __restrict__ Xg,
                                                 const float* __restrict__ bias,
                                                 f16* __restrict__ outg) {
  constexpr int MT = MODE ? SL : DA;
  constexpr int NT = MODE ? DA : SL;
  __shared__ f16 Wl[128 * 40];
  __shared__ f16 Xl[128 * 40];
  const int b = blockIdx.z;
  const int m0 = blockIdx.x * 128;
  const int n0 = blockIdx.y * 128;
  const int o_base = MODE ? n0 : m0;
  const int s_base = MODE ? m0 : n0;
  const int t = threadIdx.x;
  const int w = t >> 6, lane = t & 63, lr = lane & 15, lq = lane >> 4;
  const int wm = (w >> 1) * 64, wn = (w & 1) * 64;

  f32x4 acc[4][4] = {};

  float4 wreg[4];
  uint4 xreg[2];
  // prefetch tile 0
#pragma unroll
  for (int p = 0; p < 4; ++p) {
    const int idx = p * 256 + t;
    const int row = idx >> 3, cq = (idx & 7) * 4;
    wreg[p] = *(const float4*)&Wg[(size_t)(o_base + row) * DA + cq];
  }
#pragma unroll
  for (int p = 0; p < 2; ++p) {
    const int idx = p * 256 + t;
    const int row = idx >> 2, c8 = (idx & 3) * 8;
    xreg[p] = *(const uint4*)&Xg[((size_t)b * SL + s_base + row) * DA + c8];
  }

  for (int kt = 0; kt < 16; ++kt) {
    __syncthreads();  // all waves done reading previous tile
#pragma unroll
    for (int p = 0; p < 4; ++p) {
      const int idx = p * 256 + t;
      const int row = idx >> 3, cq = (idx & 7) * 4;
      h4_t hv;
      hv[0] = (f16)wreg[p].x; hv[1] = (f16)wreg[p].y;
      hv[2] = (f16)wreg[p].z; hv[3] = (f16)wreg[p].w;
      *(h4_t*)&Wl[row * 40 + cq] = hv;
    }
#pragma unroll
    for (int p = 0; p < 2; ++p) {
      const int idx = p * 256 + t;
      const int row = idx >> 2, c8 = (idx & 3) * 8;
      *(uint4*)&Xl[row * 40 + c8] = xreg[p];
    }
    __syncthreads();
    if (kt < 15) {  // prefetch next tile (consumed after compute + barrier)
      const int c0 = (kt + 1) * 32;
#pragma unroll
      for (int p = 0; p < 4; ++p) {
        const int idx = p * 256 + t;
        const int row = idx >> 3, cq = (idx & 7) * 4;
        wreg[p] = *(const float4*)&Wg[(size_t)(o_base + row) * DA + c0 + cq];
      }
#pragma unroll
      for (int p = 0; p < 2; ++p) {
        const int idx = p * 256 + t;
        const int row = idx >> 2, c8 = (idx & 3) * 8;
        xreg[p] = *(const uint4*)&Xg[((size_t)b * SL + s_base + row) * DA + c0 + c8];
      }
    }
    const f16* Al = MODE ? Xl : Wl;
    const f16* Bl = MODE ? Wl : Xl;
    h8_t af[4], bf[4];
#pragma unroll
    for (int i = 0; i < 4; ++i) af[i] = *(const h8_t*)&Al[(wm + i * 16 + lr) * 40 + lq * 8];
#pragma unroll
    for (int j = 0; j < 4; ++j) bf[j] = *(const h8_t*)&Bl[(wn + j * 16 + lr) * 40 + lq * 8];
#pragma unroll
    for (int i = 0; i < 4; ++i)
#pragma unroll
      for (int j = 0; j < 4; ++j)
        acc[i][j] = __builtin_amdgcn_mfma_f32_16x16x32_f16(af[i], bf[j], acc[i][j], 0, 0, 0);
  }

#pragma unroll
  for (int i = 0; i < 4; ++i) {
    const int gmb = m0 + wm + i * 16 + lq * 4;
    float bm[4] = {0.f, 0.f, 0.f, 0.f};
    if (MODE == 0) {
      const float4 b4 = *(const float4*)&bias[gmb];
      bm[0] = b4.x; bm[1] = b4.y; bm[2] = b4.z; bm[3] = b4.w;
    }
#pragma unroll
    for (int j = 0; j < 4; ++j) {
      const int gn = n0 + wn + j * 16 + lr;
      const float bn = (MODE == 1) ? bias[gn] : 0.f;
      h4_t hv;
#pragma unroll
      for (int r = 0; r < 4; ++r) {
        const float val = acc[i][j][r] + (MODE == 0 ? bm[r] : bn);
        hv[r] = (f16)val;
      }
      *(h4_t*)&outg[((size_t)b * NT + gn) * MT + gmb] = hv;
    }
  }
}

// ---------------------------------------------------------------------------
// K2: fused flash attention. grid (BS*NH, SL/256), block 256 (4 waves).
// Each wave owns 64 query rows (2 independent 32-col MFMA groups -> 2
// independent softmax chains for latency hiding). 32x32x16 MFMA, S^T = K*Q^T.
// K/V double-buffered in LDS, register prefetch, ONE barrier per j-tile.
// Q fragments built directly from global (no LDS staging).
// Epilogue bounces O through LDS for fully-coalesced 1KB-row stores.
// ---------------------------------------------------------------------------
__global__ __launch_bounds__(256, 2) void attn_kernel(
    const float* __restrict__ qg, const f16* __restrict__ kp, const f16* __restrict__ vp,
    const float* __restrict__ gamma, const float* __restrict__ gbns,
    const int* __restrict__ maskg, float* __restrict__ outg) {
  __shared__ __align__(16) char smem[75776];
  f16* Pbuf = (f16*)smem;                    // 4 waves x [64 i][72 j] = 36864 B
  f16* KV = (f16*)(smem + 36864);            // 2 bufs x (K[64][72] + V[64][72]) = 36864 B
  float* AL = (float*)(smem + 73728);        // 4 waves x 64 = 1024 B
  float* Osh = (float*)smem;                 // epilogue overlay: [32 d][260] = 33280 B

  const int bh = blockIdx.x, b = bh >> 3, h = bh & 7;
  const int i0 = blockIdx.y * 256;
  const int t = threadIdx.x, w = t >> 6, lane = t & 63;
  const int l5 = lane & 31, hf = lane >> 5;
  const float scale = gamma[h] / gbns[h] * 1.44269504088896f;  // GBN scale * log2(e)

  // ---- Q fragments straight from global (B-operand: n=i, k=d)
  h8_t qf[2][4];
#pragma unroll
  for (int im = 0; im < 2; ++im)
#pragma unroll
    for (int ks = 0; ks < 4; ++ks) {
      h8_t v;
#pragma unroll
      for (int u = 0; u < 8; ++u) {
        const int d = ks * 16 + hf * 8 + u;
        v[u] = (f16)(qg[((size_t)b * DA + h * DH + d) * SL + i0 + w * 64 + im * 32 + l5] * scale);
      }
      qf[im][ks] = v;
    }

  // ---- stage tile 0
  uint4 rk[2], rv[2];
#pragma unroll
  for (int p = 0; p < 2; ++p) {
    const int idx = p * 256 + t;
    const int row = idx >> 3, c8 = (idx & 7) * 8;
    rk[p] = *(const uint4*)&kp[((size_t)b * SL + row) * DA + h * DH + c8];
    rv[p] = *(const uint4*)&vp[((size_t)b * DA + h * DH + row) * SL + c8];
  }
  {
    f16* K0 = KV;
    f16* V0 = KV + 4608;
#pragma unroll
    for (int p = 0; p < 2; ++p) {
      const int idx = p * 256 + t;
      const int row = idx >> 3, c8 = (idx & 7) * 8;
      *(uint4*)&K0[row * 72 + c8] = rk[p];
      *(uint4*)&V0[row * 72 + c8] = rv[p];
    }
  }
  __syncthreads();

  float m_i[2] = {-3e38f, -3e38f}, l_i[2] = {0.f, 0.f};
  f32x16 acc[2][2] = {};
  f16* Pw = Pbuf + w * 4608;

  for (int jt = 0; jt < 16; ++jt) {
    const int j0 = jt * 64;
    const f16* Kc = KV + (jt & 1) * 9216;
    const f16* Vc = Kc + 4608;

    // prefetch next tile into regs (consumed at end of this iter)
    if (jt < 15) {
      const int jn = j0 + 64;
#pragma unroll
      for (int p = 0; p < 2; ++p) {
        const int idx = p * 256 + t;
        const int row = idx >> 3, c8 = (idx & 7) * 8;
        rk[p] = *(const uint4*)&kp[((size_t)b * SL + jn + row) * DA + h * DH + c8];
        rv[p] = *(const uint4*)&vp[((size_t)b * DA + h * DH + row) * SL + jn + c8];
      }
    }
    // key-mask quads (same for both im chains)
    int4 mq[8];
#pragma unroll
    for (int mj = 0; mj < 2; ++mj)
#pragma unroll
      for (int q = 0; q < 4; ++q)
        mq[mj * 4 + q] = *(const int4*)&maskg[b * SL + j0 + mj * 32 + q * 8 + hf * 4];

    // S^T = K * Q^T : rows j, cols i ; kf reused across both im groups
    f32x16 sa[2][2] = {};
#pragma unroll
    for (int ks = 0; ks < 4; ++ks)
#pragma unroll
      for (int mj = 0; mj < 2; ++mj) {
        const h8_t kf = *(const h8_t*)&Kc[(mj * 32 + l5) * 72 + ks * 16 + hf * 8];
#pragma unroll
        for (int im = 0; im < 2; ++im)
          sa[im][mj] = __builtin_amdgcn_mfma_f32_32x32x16_f16(kf, qf[im][ks], sa[im][mj], 0, 0, 0);
      }

    // key mask: reg e -> j_local = (e&3) + 8*(e>>2) + 4*hf (+32*mj)
#pragma unroll
    for (int mj = 0; mj < 2; ++mj)
#pragma unroll
      for (int q = 0; q < 4; ++q) {
        const int4 m4 = mq[mj * 4 + q];
#pragma unroll
        for (int im = 0; im < 2; ++im) {
          if (m4.x) sa[im][mj][q * 4 + 0] = -1e9f;
          if (m4.y) sa[im][mj][q * 4 + 1] = -1e9f;
          if (m4.z) sa[im][mj][q * 4 + 2] = -1e9f;
          if (m4.w) sa[im][mj][q * 4 + 3] = -1e9f;
        }
      }

    // online softmax: two independent chains (im), exp2 domain
    float al[2];
#pragma unroll
    for (int im = 0; im < 2; ++im) {
      float mx = sa[im][0][0];
#pragma unroll
      for (int e = 1; e < 16; ++e) mx = fmaxf(mx, sa[im][0][e]);
#pragma unroll
      for (int e = 0; e < 16; ++e) mx = fmaxf(mx, sa[im][1][e]);
      mx = fmaxf(mx, __shfl_xor(mx, 32));
      const float mn = fmaxf(m_i[im], mx);
      al[im] = __builtin_amdgcn_exp2f(m_i[im] - mn);
      m_i[im] = mn;
      float rs = 0.f;
#pragma unroll
      for (int mj = 0; mj < 2; ++mj)
#pragma unroll
        for (int e = 0; e < 16; ++e) {
          const float pv = __builtin_amdgcn_exp2f(sa[im][mj][e] - mn);
          sa[im][mj][e] = pv;
          rs += pv;
        }
      rs += __shfl_xor(rs, 32);
      l_i[im] = l_i[im] * al[im] + rs;
    }

    // P -> LDS (wave-private), packed b64
#pragma unroll
    for (int im = 0; im < 2; ++im)
#pragma unroll
      for (int mj = 0; mj < 2; ++mj)
#pragma unroll
        for (int q = 0; q < 4; ++q) {
          h4_t pk;
          pk[0] = (f16)sa[im][mj][q * 4 + 0];
          pk[1] = (f16)sa[im][mj][q * 4 + 1];
          pk[2] = (f16)sa[im][mj][q * 4 + 2];
          pk[3] = (f16)sa[im][mj][q * 4 + 3];
          *(h4_t*)&Pw[(im * 32 + l5) * 72 + mj * 32 + q * 8 + hf * 4] = pk;
        }

    // alpha redistribution (col layout -> row layout) via wave-private LDS
    AL[w * 64 + l5] = al[0];
    AL[w * 64 + 32 + l5] = al[1];
#pragma unroll
    for (int im = 0; im < 2; ++im) {
      f32x4 af[4];
#pragma unroll
      for (int q = 0; q < 4; ++q)
        af[q] = *(const f32x4*)&AL[w * 64 + im * 32 + q * 8 + hf * 4];
#pragma unroll
      for (int nd = 0; nd < 2; ++nd)
#pragma unroll
        for (int e = 0; e < 16; ++e) acc[im][nd][e] *= af[e >> 2][e & 3];
    }

    // O += P * V^T : vf reused across both im groups
#pragma unroll
    for (int jk = 0; jk < 4; ++jk) {
      h8_t pf[2];
#pragma unroll
      for (int im = 0; im < 2; ++im)
        pf[im] = *(const h8_t*)&Pw[(im * 32 + l5) * 72 + jk * 16 + hf * 8];
#pragma unroll
      for (int nd = 0; nd < 2; ++nd) {
        const h8_t vf = *(const h8_t*)&Vc[(nd * 32 + l5) * 72 + jk * 16 + hf * 8];
#pragma unroll
        for (int im = 0; im < 2; ++im)
          acc[im][nd] = __builtin_amdgcn_mfma_f32_32x32x16_f16(pf[im], vf, acc[im][nd], 0, 0, 0);
      }
    }

    // write prefetched tile into the other buffer; ONE barrier per tile
    if (jt < 15) {
      f16* Kn = KV + ((jt + 1) & 1) * 9216;
      f16* Vn = Kn + 4608;
#pragma unroll
      for (int p = 0; p < 2; ++p) {
        const int idx = p * 256 + t;
        const int row = idx >> 3, c8 = (idx & 7) * 8;
        *(uint4*)&Kn[row * 72 + c8] = rk[p];
        *(uint4*)&Vn[row * 72 + c8] = rv[p];
      }
      __syncthreads();
    }
  }

  // ---- epilogue: 1/l (or 0 for masked query rows), LDS bounce, coalesced store
  AL[w * 64 + l5] = l_i[0];
  AL[w * 64 + 32 + l5] = l_i[1];
  float fac[2][16];
#pragma unroll
  for (int im = 0; im < 2; ++im)
#pragma unroll
    for (int q = 0; q < 4; ++q) {
      const f32x4 lf = *(const f32x4*)&AL[w * 64 + im * 32 + q * 8 + hf * 4];
      const int4 mo = *(const int4*)&maskg[b * SL + i0 + w * 64 + im * 32 + q * 8 + hf * 4];
      fac[im][q * 4 + 0] = mo.x ? 0.f : 1.f / lf[0];
      fac[im][q * 4 + 1] = mo.y ? 0.f : 1.f / lf[1];
      fac[im][q * 4 + 2] = mo.z ? 0.f : 1.f / lf[2];
      fac[im][q * 4 + 3] = mo.w ? 0.f : 1.f / lf[3];
    }
  __syncthreads();  // all waves done with P region before Osh overlay

#pragma unroll
  for (int nd = 0; nd < 2; ++nd) {
    // stage [32 d][256 i] scaled O into LDS (stride 260)
#pragma unroll
    for (int im = 0; im < 2; ++im)
#pragma unroll
      for (int q = 0; q < 4; ++q) {
        float4 o;
        o.x = acc[im][nd][q * 4 + 0] * fac[im][q * 4 + 0];
        o.y = acc[im][nd][q * 4 + 1] * fac[im][q * 4 + 1];
        o.z = acc[im][nd][q * 4 + 2] * fac[im][q * 4 + 2];
        o.w = acc[im][nd][q * 4 + 3] * fac[im][q * 4 + 3];
        *(float4*)&Osh[l5 * 260 + w * 64 + im * 32 + q * 8 + hf * 4] = o;
      }
    __syncthreads();
    // store: 1KB contiguous per d-row, full cache lines
#pragma unroll
    for (int pass = 0; pass < 8; ++pass) {
      const int row = pass * 4 + (t >> 6);
      const int i4 = (t & 63) * 4;
      const float4 o = *(const float4*)&Osh[row * 260 + i4];
      *(float4*)&outg[((size_t)b * DA + h * DH + nd * 32 + row) * SL + i0 + i4] = o;
    }
    __syncthreads();
  }
}

// ---------------------------------------------------------------------------
extern "C" void kernel_launch(void* const* d_in, const int* in_sizes, int n_in,
                              void* d_out, int out_size, void* d_ws, size_t ws_size,
                              hipStream_t stream) {
  const float* q     = (const float*)d_in[0];
  const float* k_in  = (const float*)d_in[1];
  const float* v_in  = (const float*)d_in[2];
  const float* k_w   = (const float*)d_in[3];
  const float* k_b   = (const float*)d_in[4];
  const float* v_w   = (const float*)d_in[5];
  const float* v_b   = (const float*)d_in[6];
  const float* gamma = (const float*)d_in[7];
  const float* gbns  = (const float*)d_in[10];  // gbn_bias/gbn_m cancel under softmax
  const int*   mask  = (const int*)d_in[11];
  float* out = (float*)d_out;

  const size_t NEL = (size_t)BS * SL * DA;

  if (ws_size >= 4 * NEL * sizeof(f16)) {
    f16* XTk = (f16*)d_ws;
    f16* XTv = XTk + NEL;
    f16* kpw = XTv + NEL;
    f16* vpw = kpw + NEL;
    transpose_cast<<<dim3(SL / 64, DA / 64, 2 * BS), 256, 0, stream>>>(k_in, XTk, v_in, XTv);
    proj_gemm<0><<<dim3(4, 8, BS), 256, 0, stream>>>(k_w, XTk, k_b, kpw);
    proj_gemm<1><<<dim3(8, 4, BS), 256, 0, stream>>>(v_w, XTv, v_b, vpw);
    attn_kernel<<<dim3(BS * NH, SL / 256), 256, 0, stream>>>(q, kpw, vpw, gamma, gbns, mask, out);
  } else {
    f16* XT  = (f16*)d_ws;
    f16* kpw = XT + NEL;
    f16* vpw = kpw + NEL;
    transpose_cast<<<dim3(SL / 64, DA / 64, BS), 256, 0, stream>>>(k_in, XT, k_in, XT);
    proj_gemm<0><<<dim3(4, 8, BS), 256, 0, stream>>>(k_w, XT, k_b, kpw);
    transpose_cast<<<dim3(SL / 64, DA / 64, BS), 256, 0, stream>>>(v_in, XT, v_in, XT);
    proj_gemm<1><<<dim3(8, 4, BS), 256, 0, stream>>>(v_w, XT, v_b, vpw);
    attn_kernel<<<dim3(BS * NH, SL / 256), 256, 0, stream>>>(q, kpw, vpw, gamma, gbns, mask, out);
  }
}

// Round 4
// 260.219 us; speedup vs baseline: 1.3417x; 1.1315x over previous
//
#include <hip/hip_runtime.h>

typedef _Float16 f16;
typedef _Float16 h8_t __attribute__((ext_vector_type(8)));
typedef _Float16 h4_t __attribute__((ext_vector_type(4)));
typedef float f32x4 __attribute__((ext_vector_type(4)));
typedef float f32x16 __attribute__((ext_vector_type(16)));

#define BS 16
#define DA 512
#define SL 1024
#define NH 8
#define DH 64

// ---------------------------------------------------------------------------
// K1: FUSED transpose + projection GEMM. Reads raw f32 input [b][c][s],
// transposes a 32c x 128s tile through LDS each K-iter, MFMA 16x16x32.
// MODE 0 (k-proj): A=W (m=o, M=512), B=X^T (n=s, N=1024), out kp[b][s][o]
// MODE 1 (v-proj): A=X^T (m=s, M=1024), B=W (n=o, N=512), out vp[b][o][s]
// grid (M/128, N/128, BS), block 256 (4 waves, each 64x64). Simple 3-barrier
// structure (R3's reg-prefetch variant regressed ~20us; reverted).
// ---------------------------------------------------------------------------
template <int MODE>
__global__ __launch_bounds__(256) void fused_proj(const float* __restrict__ Wg,
                                                  const float* __restrict__ Xin,
                                                  const float* __restrict__ bias,
                                                  f16* __restrict__ outg) {
  constexpr int MT = MODE ? SL : DA;
  constexpr int NT = MODE ? DA : SL;
  __shared__ f16 Wl[128 * 40];     // [o][c] f16
  __shared__ f16 Xl[128 * 40];     // [s][c] f16 (transposed)
  __shared__ float Xf32[32 * 132]; // [c][s] staging
  const int b = blockIdx.z;
  const int m0 = blockIdx.x * 128;
  const int n0 = blockIdx.y * 128;
  const int o_base = MODE ? n0 : m0;
  const int s_base = MODE ? m0 : n0;
  const int t = threadIdx.x;
  const int w = t >> 6, lane = t & 63, lr = lane & 15, lq = lane >> 4;
  const int wm = (w >> 1) * 64, wn = (w & 1) * 64;

  f32x4 acc[4][4] = {};

  for (int kt = 0; kt < 16; ++kt) {
    const int c0 = kt * 32;
    __syncthreads();  // prev iter's Xf32 reads + Wl MFMA reads done
    // stage W tile (128 o x 32 c, f32 -> f16)
#pragma unroll
    for (int p = 0; p < 4; ++p) {
      const int idx = p * 256 + t;
      const int row = idx >> 3, cq = (idx & 7) * 4;
      const float4 v = *(const float4*)&Wg[(size_t)(o_base + row) * DA + c0 + cq];
      h4_t hv;
      hv[0] = (f16)v.x; hv[1] = (f16)v.y; hv[2] = (f16)v.z; hv[3] = (f16)v.w;
      *(h4_t*)&Wl[row * 40 + cq] = hv;
    }
    // stage1: X f32 tile [32 c][128 s], coalesced along s
#pragma unroll
    for (int p = 0; p < 4; ++p) {
      const int idx = p * 256 + t;
      const int cc = idx >> 5, s4 = (idx & 31) * 4;
      const float4 v = *(const float4*)&Xin[((size_t)b * DA + c0 + cc) * SL + s_base + s4];
      *(float4*)&Xf32[cc * 132 + s4] = v;
    }
    __syncthreads();
    // stage2: transpose to Xl [s][c] f16 (reads 2-way conflict-free)
    {
      const int srow = t >> 1, cb = (t & 1) * 16;
      h8_t lo, hi;
#pragma unroll
      for (int u = 0; u < 8; ++u) lo[u] = (f16)Xf32[(cb + u) * 132 + srow];
#pragma unroll
      for (int u = 0; u < 8; ++u) hi[u] = (f16)Xf32[(cb + 8 + u) * 132 + srow];
      *(h8_t*)&Xl[srow * 40 + cb] = lo;
      *(h8_t*)&Xl[srow * 40 + cb + 8] = hi;
    }
    __syncthreads();
    const f16* Al = MODE ? Xl : Wl;
    const f16* Bl = MODE ? Wl : Xl;
    h8_t af[4], bf[4];
#pragma unroll
    for (int i = 0; i < 4; ++i) af[i] = *(const h8_t*)&Al[(wm + i * 16 + lr) * 40 + lq * 8];
#pragma unroll
    for (int j = 0; j < 4; ++j) bf[j] = *(const h8_t*)&Bl[(wn + j * 16 + lr) * 40 + lq * 8];
#pragma unroll
    for (int i = 0; i < 4; ++i)
#pragma unroll
      for (int j = 0; j < 4; ++j)
        acc[i][j] = __builtin_amdgcn_mfma_f32_16x16x32_f16(af[i], bf[j], acc[i][j], 0, 0, 0);
  }

  // epilogue: D row = gm (4 consecutive per lane -> 8B f16 stores), col = gn
#pragma unroll
  for (int i = 0; i < 4; ++i) {
    const int gmb = m0 + wm + i * 16 + lq * 4;
    float bm[4] = {0.f, 0.f, 0.f, 0.f};
    if (MODE == 0) {
      const float4 b4 = *(const float4*)&bias[gmb];
      bm[0] = b4.x; bm[1] = b4.y; bm[2] = b4.z; bm[3] = b4.w;
    }
#pragma unroll
    for (int j = 0; j < 4; ++j) {
      const int gn = n0 + wn + j * 16 + lr;
      const float bn = (MODE == 1) ? bias[gn] : 0.f;
      h4_t hv;
#pragma unroll
      for (int r = 0; r < 4; ++r) {
        const float val = acc[i][j][r] + (MODE == 0 ? bm[r] : bn);
        hv[r] = (f16)val;
      }
      *(h4_t*)&outg[((size_t)b * NT + gn) * MT + gmb] = hv;
    }
  }
}

// ---------------------------------------------------------------------------
// K2: fused flash attention. grid (BS*NH, SL/256), block 256 (4 waves x 64 i).
// 32x32x16 MFMA, S^T = K*Q^T with sigma-PERMUTED K rows (bits 2<->3 swapped):
// the D-layout -> PV-B-operand permutations cancel, so P goes straight from
// registers into the PV MFMA (no LDS round-trip), and PV output cols = i =
// lane, making alpha/l per-lane scalars (no redistribution LDS).
// LDS = K/V double-buffer only (36.9 KB). One barrier per j-tile.
// ---------------------------------------------------------------------------
__global__ __launch_bounds__(256, 2) void attn_kernel(
    const float* __restrict__ qg, const f16* __restrict__ kp, const f16* __restrict__ vp,
    const float* __restrict__ gamma, const float* __restrict__ gbns,
    const int* __restrict__ maskg, float* __restrict__ outg) {
  __shared__ __align__(16) char smem[36864];
  f16* KV = (f16*)smem;       // 2 bufs x (K[64][72] + V[64][72]) f16
  float* Osh = (float*)smem;  // epilogue overlay [32 d][256 i] f32

  const int bh = blockIdx.x, b = bh >> 3, h = bh & 7;
  const int i0 = blockIdx.y * 256;
  const int t = threadIdx.x, w = t >> 6, lane = t & 63;
  const int l5 = lane & 31, hf = lane >> 5;
  const float scale = gamma[h] / gbns[h] * 1.44269504088896f;  // GBN scale * log2(e)

  // ---- Q fragments straight from global (B-operand: n=i, k=d)
  h8_t qf[2][4];
#pragma unroll
  for (int im = 0; im < 2; ++im)
#pragma unroll
    for (int ks = 0; ks < 4; ++ks) {
      h8_t v;
#pragma unroll
      for (int u = 0; u < 8; ++u) {
        const int d = ks * 16 + hf * 8 + u;
        v[u] = (f16)(qg[((size_t)b * DA + h * DH + d) * SL + i0 + w * 64 + im * 32 + l5] * scale);
      }
      qf[im][ks] = v;
    }

  const int srow = t >> 3;        // 0..31 (p adds 32)
  const int c8 = (t & 7) * 8;

  // ---- stage tile 0 (K rows sigma-permuted: swap bits 2,3)
  uint4 rk[2], rv[2];
#pragma unroll
  for (int p = 0; p < 2; ++p) {
    const int row = p * 32 + srow;
    rk[p] = *(const uint4*)&kp[((size_t)b * SL + row) * DA + h * DH + c8];
    rv[p] = *(const uint4*)&vp[((size_t)b * DA + h * DH + row) * SL + c8];
  }
  {
    f16* K0 = KV;
    f16* V0 = KV + 4608;
#pragma unroll
    for (int p = 0; p < 2; ++p) {
      const int row = p * 32 + srow;
      const int rowp = (row & ~12) | ((row & 4) << 1) | ((row & 8) >> 1);
      *(uint4*)&K0[rowp * 72 + c8] = rk[p];
      *(uint4*)&V0[row * 72 + c8] = rv[p];
    }
  }
  __syncthreads();

  float m_i[2] = {-3e38f, -3e38f}, l_i[2] = {0.f, 0.f};
  f32x16 acc[2][2] = {};  // [im][nd]: rows d = nd*32 + r(e,hf), col i = lane

  for (int jt = 0; jt < 16; ++jt) {
    const int j0 = jt * 64;
    const f16* Kc = KV + (jt & 1) * 9216;
    const f16* Vc = Kc + 4608;

    // prefetch next tile into regs (written at loop bottom)
    if (jt < 15) {
      const int jn = j0 + 64;
#pragma unroll
      for (int p = 0; p < 2; ++p) {
        const int row = p * 32 + srow;
        rk[p] = *(const uint4*)&kp[((size_t)b * SL + jn + row) * DA + h * DH + c8];
        rv[p] = *(const uint4*)&vp[((size_t)b * DA + h * DH + row) * SL + jn + c8];
      }
    }
    // key-mask quads, sigma-mapped: reg e=q*4+r <-> j = mj*32+16(q>>1)+8hf+4(q&1)+r
    int4 mq[2][4];
#pragma unroll
    for (int mj = 0; mj < 2; ++mj)
#pragma unroll
      for (int q = 0; q < 4; ++q)
        mq[mj][q] = *(const int4*)&maskg[b * SL + j0 + mj * 32 + (q >> 1) * 16 + hf * 8 + (q & 1) * 4];

    // S^T = K * Q^T : rows = permuted K rows, cols = i
    f32x16 sa[2][2] = {};
#pragma unroll
    for (int ks = 0; ks < 4; ++ks)
#pragma unroll
      for (int mj = 0; mj < 2; ++mj) {
        const h8_t kf = *(const h8_t*)&Kc[(mj * 32 + l5) * 72 + ks * 16 + hf * 8];
#pragma unroll
        for (int im = 0; im < 2; ++im)
          sa[im][mj] = __builtin_amdgcn_mfma_f32_32x32x16_f16(kf, qf[im][ks], sa[im][mj], 0, 0, 0);
      }

    // key mask
#pragma unroll
    for (int mj = 0; mj < 2; ++mj)
#pragma unroll
      for (int q = 0; q < 4; ++q) {
        const int4 m4 = mq[mj][q];
#pragma unroll
        for (int im = 0; im < 2; ++im) {
          if (m4.x) sa[im][mj][q * 4 + 0] = -1e9f;
          if (m4.y) sa[im][mj][q * 4 + 1] = -1e9f;
          if (m4.z) sa[im][mj][q * 4 + 2] = -1e9f;
          if (m4.w) sa[im][mj][q * 4 + 3] = -1e9f;
        }
      }

    // online softmax, two independent chains; exp2 domain; per-lane i = l5
    float alpha[2];
#pragma unroll
    for (int im = 0; im < 2; ++im) {
      float mx = sa[im][0][0];
#pragma unroll
      for (int e = 1; e < 16; ++e) mx = fmaxf(mx, sa[im][0][e]);
#pragma unroll
      for (int e = 0; e < 16; ++e) mx = fmaxf(mx, sa[im][1][e]);
      mx = fmaxf(mx, __shfl_xor(mx, 32));
      const float mn = fmaxf(m_i[im], mx);
      alpha[im] = __builtin_amdgcn_exp2f(m_i[im] - mn);
      m_i[im] = mn;
      float rs = 0.f;
#pragma unroll
      for (int mj = 0; mj < 2; ++mj)
#pragma unroll
        for (int e = 0; e < 16; ++e) {
          const float pv = __builtin_amdgcn_exp2f(sa[im][mj][e] - mn);
          sa[im][mj][e] = pv;
          rs += pv;
        }
      rs += __shfl_xor(rs, 32);
      l_i[im] = l_i[im] * alpha[im] + rs;
      // rescale O accumulator: per-lane scalar!
#pragma unroll
      for (int nd = 0; nd < 2; ++nd)
#pragma unroll
        for (int e = 0; e < 16; ++e) acc[im][nd][e] *= alpha[im];
    }

    // O^T += V^T * P^T : A = V^T[d][j] from LDS, B = P^T straight from regs
    // (sigma cancellation: B slot k holds logical j = k)
#pragma unroll
    for (int jk = 0; jk < 4; ++jk) {
      const int mj = jk >> 1, g = jk & 1;
      h8_t pf[2];
#pragma unroll
      for (int im = 0; im < 2; ++im) {
        h8_t pk;
#pragma unroll
        for (int u = 0; u < 8; ++u) pk[u] = (f16)sa[im][mj][g * 8 + u];
        pf[im] = pk;
      }
#pragma unroll
      for (int nd = 0; nd < 2; ++nd) {
        const h8_t vf = *(const h8_t*)&Vc[(nd * 32 + l5) * 72 + jk * 16 + hf * 8];
#pragma unroll
        for (int im = 0; im < 2; ++im)
          acc[im][nd] = __builtin_amdgcn_mfma_f32_32x32x16_f16(vf, pf[im], acc[im][nd], 0, 0, 0);
      }
    }

    // write prefetched tile into the other buffer; ONE barrier per tile
    if (jt < 15) {
      f16* Kn = KV + ((jt + 1) & 1) * 9216;
      f16* Vn = Kn + 4608;
#pragma unroll
      for (int p = 0; p < 2; ++p) {
        const int row = p * 32 + srow;
        const int rowp = (row & ~12) | ((row & 4) << 1) | ((row & 8) >> 1);
        *(uint4*)&Kn[rowp * 72 + c8] = rk[p];
        *(uint4*)&Vn[row * 72 + c8] = rv[p];
      }
      __syncthreads();
    }
  }

  // ---- epilogue: per-lane 1/l (0 for masked query rows), LDS bounce per nd
  float fac[2];
#pragma unroll
  for (int im = 0; im < 2; ++im) {
    const int mo = maskg[b * SL + i0 + w * 64 + im * 32 + l5];
    fac[im] = mo ? 0.f : 1.f / l_i[im];
  }
  __syncthreads();  // all waves done reading KV before Osh overlay

#pragma unroll
  for (int nd = 0; nd < 2; ++nd) {
    // scatter acc into Osh [d_local][i_block] (2-way conflicts only)
#pragma unroll
    for (int im = 0; im < 2; ++im)
#pragma unroll
      for (int e = 0; e < 16; ++e) {
        const int dl = (e & 3) + 8 * (e >> 2) + 4 * hf;
        Osh[dl * 256 + w * 64 + im * 32 + l5] = acc[im][nd][e] * fac[im];
      }
    __syncthreads();
    // coalesced store: 1KB contiguous per d-row
#pragma unroll
    for (int pass = 0; pass < 8; ++pass) {
      const int row = pass * 4 + w;
      const int i4 = lane * 4;
      const float4 o = *(const float4*)&Osh[row * 256 + i4];
      *(float4*)&outg[((size_t)b * DA + h * DH + nd * 32 + row) * SL + i0 + i4] = o;
    }
    __syncthreads();  // before next nd pass overwrites Osh
  }
}

// ---------------------------------------------------------------------------
extern "C" void kernel_launch(void* const* d_in, const int* in_sizes, int n_in,
                              void* d_out, int out_size, void* d_ws, size_t ws_size,
                              hipStream_t stream) {
  const float* q     = (const float*)d_in[0];
  const float* k_in  = (const float*)d_in[1];
  const float* v_in  = (const float*)d_in[2];
  const float* k_w   = (const float*)d_in[3];
  const float* k_b   = (const float*)d_in[4];
  const float* v_w   = (const float*)d_in[5];
  const float* v_b   = (const float*)d_in[6];
  const float* gamma = (const float*)d_in[7];
  const float* gbns  = (const float*)d_in[10];  // gbn_bias/gbn_m cancel under softmax
  const int*   mask  = (const int*)d_in[11];
  float* out = (float*)d_out;

  const size_t NEL = (size_t)BS * SL * DA;
  f16* kpw = (f16*)d_ws;        // k projection, [b][s][o], 16 MiB
  f16* vpw = kpw + NEL;         // v projection, [b][o][s], 16 MiB

  fused_proj<0><<<dim3(4, 8, BS), 256, 0, stream>>>(k_w, k_in, k_b, kpw);
  fused_proj<1><<<dim3(8, 4, BS), 256, 0, stream>>>(v_w, v_in, v_b, vpw);
  attn_kernel<<<dim3(BS * NH, SL / 256), 256, 0, stream>>>(q, kpw, vpw, gamma, gbns, mask, out);
}